// Round 1
// baseline (8931.725 us; speedup 1.0000x reference)
//
#include <hip/hip_runtime.h>

// Decoder_8014408974552: fused 30-step GRU rollout, bf16 MFMA, MI355X (gfx950).
//
// B=32768 rows, each independent => one persistent kernel, grid over batch,
// t-loop inside. Each wave owns 16 rows for everything (no cross-wave deps).
// Hidden state: wave-private LDS (bf16, padded k-tile blocks) + register
// A-fragments. GRU blend done in C-layout in place (same lane, same address).
// Weights converted to bf16 once per launch into d_ws (~1.24 MB needed).

#define TT 30
#define HB 40            // hbuf row stride in u16 (32 cols + 8 pad)
#define HBLK (16*HB)     // one k-tile block (16 rows)

typedef unsigned short u16;
typedef __bf16 bf16x8 __attribute__((ext_vector_type(8)));
typedef u16    u16x8  __attribute__((ext_vector_type(8)));
typedef float  f32x4  __attribute__((ext_vector_type(4)));

__device__ __forceinline__ u16 f2b(float f){           // fp32 -> bf16 RNE
  unsigned u = __float_as_uint(f);
  u += 0x7FFFu + ((u >> 16) & 1u);
  return (u16)(u >> 16);
}
__device__ __forceinline__ float b2f(u16 h){ return __uint_as_float(((unsigned)h) << 16); }

__device__ __forceinline__ f32x4 mfma16(u16x8 a, u16x8 b, f32x4 c){
  return __builtin_amdgcn_mfma_f32_16x16x32_bf16(
      __builtin_bit_cast(bf16x8, a), __builtin_bit_cast(bf16x8, b), c, 0, 0, 0);
}
__device__ __forceinline__ void lds_fence(){ asm volatile("s_waitcnt lgkmcnt(0)" ::: "memory"); }
__device__ __forceinline__ float sigf(float x){ return __builtin_amdgcn_rcpf(1.f + __expf(-x)); }
__device__ __forceinline__ float tanh_(float x){ return 2.f*__builtin_amdgcn_rcpf(1.f + __expf(-2.f*x)) - 1.f; }

// ---------------------------------------------------------------- prep ----
__global__ void prep_kernel(const float* __restrict__ Wih, const float* __restrict__ Whh,
                            const float* __restrict__ Wd1,
                            const float* __restrict__ bih, const float* __restrict__ bhh,
                            const float* __restrict__ Ws,  const float* __restrict__ bs,
                            const float* __restrict__ Wp,  const float* __restrict__ bp,
                            u16* __restrict__ wih_b, u16* __restrict__ whh_b,
                            u16* __restrict__ wd1_b, float* __restrict__ wxc,
                            float* __restrict__ gb)
{
  int i = blockIdx.x*blockDim.x + threadIdx.x;
  if (i < 442368) whh_b[i] = f2b(Whh[i]);   // [1152][384]
  if (i < 147456) wih_b[i] = f2b(Wih[i]);   // [1152][128]
  if (i < 24576)  wd1_b[i] = f2b(Wd1[i]);   // [64][384]
  if (i < 128){   // packed x-MLP weights: {Ws0..2, bs, Wp0..2, bp} per col
    wxc[i*8+0]=Ws[i*3+0]; wxc[i*8+1]=Ws[i*3+1]; wxc[i*8+2]=Ws[i*3+2]; wxc[i*8+3]=bs[i];
    wxc[i*8+4]=Wp[i*3+0]; wxc[i*8+5]=Wp[i*3+1]; wxc[i*8+6]=Wp[i*3+2]; wxc[i*8+7]=bp[i];
  }
  if (i < 384){   // fused gate biases per hidden unit: {r, z, n_i, n_h}
    gb[i*4+0] = bih[i]       + bhh[i];
    gb[i*4+1] = bih[384+i]   + bhh[384+i];
    gb[i*4+2] = bih[768+i];
    gb[i*4+3] = bhh[768+i];
  }
}

// ---------------------------------------------------------------- main ----
__global__ __launch_bounds__(256, 2)
void gru_main(const float* __restrict__ ih, const float* __restrict__ plan,
              const float* __restrict__ gate, const float* __restrict__ istate,
              const u16* __restrict__ Wih, const u16* __restrict__ Whh,
              const u16* __restrict__ Wd1, const float* __restrict__ Wd2,
              const float* __restrict__ wxc, const float* __restrict__ gb,
              const float* __restrict__ bd1, const float* __restrict__ bd2,
              float* __restrict__ out)
{
  __shared__ __attribute__((aligned(16))) u16 hbuf[4][12*HBLK]; // 61440 B
  __shared__ float sstate[4][16][4];                            // 1024 B

  const int tid  = threadIdx.x;
  const int wave = tid >> 6;
  const int lane = tid & 63;
  const int q    = lane >> 4;   // quad
  const int lr   = lane & 15;
  const int R0   = blockIdx.x*64 + wave*16;   // this wave's 16 batch rows

  u16* hb = hbuf[wave];

  // hoisted per-lane constants (weights are launch-invariant)
  float w2[3][4];
#pragma unroll
  for (int o=0;o<3;++o)
#pragma unroll
    for (int nt=0;nt<4;++nt) w2[o][nt] = Wd2[o*64 + nt*16 + lr];
  float bd1r[4];
#pragma unroll
  for (int nt=0;nt<4;++nt) bd1r[nt] = bd1[nt*16 + lr];
  const float bd2r = bd2[lr < 3 ? lr : 0];
  const float g    = gate[R0 + lr];

  if (lane < 16){
    const float* sp = istate + (size_t)(R0+lane)*3;
    sstate[wave][lane][0] = sp[0];
    sstate[wave][lane][1] = sp[1];
    sstate[wave][lane][2] = sp[2];
    sstate[wave][lane][3] = 0.f;
  }

  // init hidden -> LDS (bf16), then register A-fragments
#pragma unroll
  for (int kt=0; kt<12; ++kt){
    const float* p = ih + (size_t)(R0+lr)*384 + kt*32 + q*8;
    float4 a = *(const float4*)p;
    float4 b = *(const float4*)(p+4);
    u16x8 v;
    v[0]=f2b(a.x); v[1]=f2b(a.y); v[2]=f2b(a.z); v[3]=f2b(a.w);
    v[4]=f2b(b.x); v[5]=f2b(b.y); v[6]=f2b(b.z); v[7]=f2b(b.w);
    *(u16x8*)&hb[kt*HBLK + lr*HB + q*8] = v;
  }
  lds_fence();
  u16x8 hf[12];
#pragma unroll
  for (int kt=0; kt<12; ++kt) hf[kt] = *(const u16x8*)&hb[kt*HBLK + lr*HB + q*8];
  __syncthreads();

  for (int t=0; t<TT; ++t){
    // ---- x = (state@Ws^T + bs) + gate*(plan_t@Wp^T + bp), straight into A-frags
    float s0 = sstate[wave][lr][0];
    float s1 = sstate[wave][lr][1];
    float s2 = sstate[wave][lr][2];
    const float* pp = plan + (size_t)(R0+lr)*(TT*3) + t*3;
    float p0 = pp[0], p1 = pp[1], p2 = pp[2];
    u16x8 xf[4];
#pragma unroll
    for (int kt=0; kt<4; ++kt){
      u16x8 v;
#pragma unroll
      for (int j=0; j<8; ++j){
        int u = kt*32 + q*8 + j;
        const float* w = wxc + u*8;
        float4 wa = *(const float4*)w;
        float4 wb = *(const float4*)(w+4);
        float x = (s0*wa.x + s1*wa.y + s2*wa.z + wa.w)
                + g*(p0*wb.x + p1*wb.y + p2*wb.z + wb.w);
        v[j] = f2b(x);
      }
      xf[kt] = v;
    }

    // ---- gate GEMMs + GRU elementwise, 12 column-chunks of 32 units
#pragma unroll 1
    for (int c=0; c<12; ++c){
      const int col0 = c*32;
      f32x4 aR[2], aZ[2], aNI[2], aNH[2];
#pragma unroll
      for (int nt=0; nt<2; ++nt){
        float4 bias = *(const float4*)(gb + (size_t)(col0 + nt*16 + lr)*4);
        aR[nt]  = (f32x4){bias.x, bias.x, bias.x, bias.x};
        aZ[nt]  = (f32x4){bias.y, bias.y, bias.y, bias.y};
        aNI[nt] = (f32x4){bias.z, bias.z, bias.z, bias.z};
        aNH[nt] = (f32x4){bias.w, bias.w, bias.w, bias.w};
      }
      // gi = x @ W_ih^T (K=128)
#pragma unroll
      for (int kt=0; kt<4; ++kt){
        u16x8 a = xf[kt];
#pragma unroll
        for (int nt=0; nt<2; ++nt){
          const int row = col0 + nt*16 + lr;
          const int ko  = kt*32 + q*8;
          u16x8 bR = *(const u16x8*)(Wih + (size_t)row      *128 + ko);
          u16x8 bZ = *(const u16x8*)(Wih + (size_t)(row+384)*128 + ko);
          u16x8 bN = *(const u16x8*)(Wih + (size_t)(row+768)*128 + ko);
          aR[nt]  = mfma16(a, bR, aR[nt]);
          aZ[nt]  = mfma16(a, bZ, aZ[nt]);
          aNI[nt] = mfma16(a, bN, aNI[nt]);
        }
      }
      // gh = h @ W_hh^T (K=384)
#pragma unroll
      for (int kt=0; kt<12; ++kt){
        u16x8 a = hf[kt];
#pragma unroll
        for (int nt=0; nt<2; ++nt){
          const int row = col0 + nt*16 + lr;
          const int ko  = kt*32 + q*8;
          u16x8 bR = *(const u16x8*)(Whh + (size_t)row      *384 + ko);
          u16x8 bZ = *(const u16x8*)(Whh + (size_t)(row+384)*384 + ko);
          u16x8 bN = *(const u16x8*)(Whh + (size_t)(row+768)*384 + ko);
          aR[nt]  = mfma16(a, bR, aR[nt]);
          aZ[nt]  = mfma16(a, bZ, aZ[nt]);
          aNH[nt] = mfma16(a, bN, aNH[nt]);
        }
      }
      // GRU elementwise, in-place h update (C-layout: row=q*4+r, col=lr)
#pragma unroll
      for (int nt=0; nt<2; ++nt){
#pragma unroll
        for (int r=0; r<4; ++r){
          const int row = q*4 + r;
          float rr = sigf(aR[nt][r]);
          float zz = sigf(aZ[nt][r]);
          float nn = tanh_(aNI[nt][r] + rr*aNH[nt][r]);
          const int off = c*HBLK + row*HB + nt*16 + lr;
          float ho = b2f(hb[off]);                 // old h (read before write, same lane)
          hb[off] = f2b((1.f - zz)*nn + zz*ho);    // new h
        }
      }
    }
    lds_fence();
#pragma unroll
    for (int kt=0; kt<12; ++kt) hf[kt] = *(const u16x8*)&hb[kt*HBLK + lr*HB + q*8]; // new h frags

    // ---- decode: d1 = elu(h@Wd1^T + bd1); out_delta = d1@Wd2^T + bd2
    f32x4 a1[4];
#pragma unroll
    for (int nt=0; nt<4; ++nt) a1[nt] = (f32x4){bd1r[nt], bd1r[nt], bd1r[nt], bd1r[nt]};
#pragma unroll
    for (int kt=0; kt<12; ++kt){
      u16x8 a = hf[kt];
#pragma unroll
      for (int nt=0; nt<4; ++nt){
        u16x8 b = *(const u16x8*)(Wd1 + (size_t)(nt*16+lr)*384 + kt*32 + q*8);
        a1[nt] = mfma16(a, b, a1[nt]);
      }
    }
    float d2[3][4];
#pragma unroll
    for (int o=0;o<3;++o)
#pragma unroll
      for (int r=0;r<4;++r) d2[o][r] = 0.f;
#pragma unroll
    for (int nt=0; nt<4; ++nt){
#pragma unroll
      for (int r=0; r<4; ++r){
        float e = a1[nt][r];
        e = e > 0.f ? e : (__expf(e) - 1.f);       // elu
        d2[0][r] += e * w2[0][nt];
        d2[1][r] += e * w2[1][nt];
        d2[2][r] += e * w2[2][nt];
      }
    }
    // reduce K=64 across the 16 lanes of each quad
#pragma unroll
    for (int m=1; m<16; m<<=1){
#pragma unroll
      for (int o=0;o<3;++o)
#pragma unroll
        for (int r=0;r<4;++r) d2[o][r] += __shfl_xor(d2[o][r], m, 64);
    }
    if (lr < 3){
#pragma unroll
      for (int r=0; r<4; ++r){
        const int row = q*4 + r;
        float ns = sstate[wave][row][lr] + d2[lr][r] + bd2r;
        out[(size_t)(R0+row)*(TT*3) + t*3 + lr] = ns;
        sstate[wave][row][lr] = ns;
      }
    }
    __syncthreads();   // align waves per step (L1 weight reuse) + LDS fence
  }
}

// -------------------------------------------------------------- launch ----
extern "C" void kernel_launch(void* const* d_in, const int* in_sizes, int n_in,
                              void* d_out, int out_size, void* d_ws, size_t ws_size,
                              hipStream_t stream)
{
  (void)in_sizes; (void)n_in; (void)out_size; (void)ws_size;
  const float* ih     = (const float*)d_in[0];
  const float* plan   = (const float*)d_in[1];
  const float* gatep  = (const float*)d_in[2];
  const float* istate = (const float*)d_in[3];
  const float* Wp     = (const float*)d_in[4];
  const float* bp     = (const float*)d_in[5];
  const float* Ws     = (const float*)d_in[6];
  const float* bs     = (const float*)d_in[7];
  const float* Wih    = (const float*)d_in[8];
  const float* bih    = (const float*)d_in[9];
  const float* Whh    = (const float*)d_in[10];
  const float* bhh    = (const float*)d_in[11];
  const float* Wd1    = (const float*)d_in[12];
  const float* bd1    = (const float*)d_in[13];
  const float* Wd2    = (const float*)d_in[14];
  const float* bd2    = (const float*)d_in[15];

  // workspace layout (needs ~1.24 MB)
  u16*   whh_b = (u16*)d_ws;                                  // 442368 u16
  u16*   wih_b = whh_b + 442368;                              // 147456 u16
  u16*   wd1_b = wih_b + 147456;                              //  24576 u16
  float* wxc   = (float*)((char*)d_ws + 1228800);             //   1024 f32
  float* gb    = (float*)((char*)d_ws + 1232896);             //   1536 f32

  prep_kernel<<<1728, 256, 0, stream>>>(Wih, Whh, Wd1, bih, bhh, Ws, bs, Wp, bp,
                                        wih_b, whh_b, wd1_b, wxc, gb);
  gru_main<<<512, 256, 0, stream>>>(ih, plan, gatep, istate,
                                    wih_b, whh_b, wd1_b, Wd2,
                                    wxc, gb, bd1, bd2, (float*)d_out);
}

// Round 2
// 4841.200 us; speedup vs baseline: 1.8449x; 1.8449x over previous
//
#include <hip/hip_runtime.h>

// Decoder_8014408974552 R2: fused 30-step GRU rollout, 32x32x16 bf16 MFMA,
// block-cooperative LDS weight streaming (global_load_lds, frag-major
// pre-swizzled stream), M=32 rows/wave, h in register A-frags.
//
// Grid: 256 blocks x 256 thr (4 waves x 32 rows = 128 rows/block).
// Weight stream: 50 phases/step x 24576 B, double-buffered in LDS.

#define TT  30
#define NPH 50
#define PHU 12288   // u16 per phase (24576 B)

typedef unsigned short u16;
typedef __bf16 bf16x8 __attribute__((ext_vector_type(8)));
typedef u16    u16x8  __attribute__((ext_vector_type(8)));
typedef float  f32x16 __attribute__((ext_vector_type(16)));

__device__ __forceinline__ u16 f2b(float f){           // fp32 -> bf16 RNE
  unsigned u = __float_as_uint(f);
  u += 0x7FFFu + ((u >> 16) & 1u);
  return (u16)(u >> 16);
}
__device__ __forceinline__ float b2f(u16 h){ return __uint_as_float(((unsigned)h) << 16); }

__device__ __forceinline__ f32x16 mfma32(u16x8 a, u16x8 b, f32x16 c){
  return __builtin_amdgcn_mfma_f32_32x32x16_bf16(
      __builtin_bit_cast(bf16x8, a), __builtin_bit_cast(bf16x8, b), c, 0, 0, 0);
}
__device__ __forceinline__ void lds_fence(){ asm volatile("s_waitcnt lgkmcnt(0)" ::: "memory"); }
__device__ __forceinline__ void vm_fence(){ asm volatile("s_waitcnt vmcnt(0)" ::: "memory"); }
__device__ __forceinline__ float sigf(float x){ return __builtin_amdgcn_rcpf(1.f + __expf(-x)); }
__device__ __forceinline__ float tanh_(float x){ return 2.f*__builtin_amdgcn_rcpf(1.f + __expf(-2.f*x)) - 1.f; }

__device__ __forceinline__ void stage16(const u16* g, u16* l){
  __builtin_amdgcn_global_load_lds(
      (const __attribute__((address_space(1))) unsigned int*)g,
      (__attribute__((address_space(3))) unsigned int*)l, 16, 0, 0);
}

// ---------------------------------------------------------------- prep ----
// Swizzle all weights into frag-major stream:
//   phase layout per step (50 phases x 24 frags x 1024B):
//     c*4+0 : gi  [gi_r kf0..7][gi_z kf0..7][gi_n kf0..7]   (K=128)
//     c*4+1 : gh_r kf0..23                                   (K=384)
//     c*4+2 : gh_z kf0..23
//     c*4+3 : gh_n kf0..23
//     48,49 : Wd1 col-tile 0,1  kf0..23
//   within frag: u16 index (lane&31 + 32*(lane>>5))*8 + j  ->  B[k][n]:
//     n = c*32 + (lane&31),  k = kf*16 + (lane>>5)*8 + j
__global__ void prep_kernel(const float* __restrict__ Wih, const float* __restrict__ Whh,
                            const float* __restrict__ Wd1, const float* __restrict__ Wd2,
                            const float* __restrict__ bih, const float* __restrict__ bhh,
                            const float* __restrict__ Ws,  const float* __restrict__ bs,
                            const float* __restrict__ Wp,  const float* __restrict__ bp,
                            u16* __restrict__ stream, u16* __restrict__ wd2p,
                            u16* __restrict__ wxp, float* __restrict__ gb)
{
  int i = blockIdx.x*blockDim.x + threadIdx.x;
  if (i < 442368){  // W_hh [1152][384]
    int row = i/384, k = i - row*384;
    int g = row/384, unit = row - g*384, c = unit>>5, lc = unit&31;
    int kf = k>>4, hl = (k>>3)&1, j = k&7;
    int phase = c*4 + 1 + g;
    stream[(size_t)phase*PHU + kf*512 + (lc+32*hl)*8 + j] = f2b(Whh[i]);
  }
  if (i < 147456){  // W_ih [1152][128]
    int row = i>>7, k = i&127;
    int g = row/384, unit = row - g*384, c = unit>>5, lc = unit&31;
    int kf = k>>4, hl = (k>>3)&1, j = k&7;
    int phase = c*4;
    stream[(size_t)phase*PHU + (g*8+kf)*512 + (lc+32*hl)*8 + j] = f2b(Wih[i]);
  }
  if (i < 24576){   // Wd1 [64][384]
    int row = i/384, k = i - row*384;
    int ct = row>>5, lc = row&31;
    int kf = k>>4, hl = (k>>3)&1, j = k&7;
    int phase = 48 + ct;
    stream[(size_t)phase*PHU + kf*512 + (lc+32*hl)*8 + j] = f2b(Wd1[i]);
  }
  if (i < 2048){    // Wd2 padded B-frags [4 kf][512] (n>=3 -> 0)
    int kf = i>>9, r = i&511;
    int n = (r>>3)&31, hl = r>>8, j = r&7;
    int k = kf*16 + hl*8 + j;
    wd2p[i] = f2b((n<3) ? Wd2[n*64 + k] : 0.f);
  }
  if (i < 2048){    // x-MLP B-frags [4 tiles][512]: K=16 (k=0..7 feat, 8..15 zero)
    int tl = i>>9, r = i&511;
    int n = (r>>3)&31, hl = r>>8, j = r&7;
    int k = hl*8 + j, u = tl*32 + n;
    float v = 0.f;
    if      (k <= 2) v = Ws[u*3 + k];
    else if (k == 3) v = bs[u];
    else if (k <= 6) v = Wp[u*3 + (k-4)];
    else if (k == 7) v = bp[u];
    wxp[i] = f2b(v);
  }
  if (i < 384){     // fused gate biases per hidden unit: {r, z, n_i, n_h}
    gb[i*4+0] = bih[i]       + bhh[i];
    gb[i*4+1] = bih[384+i]   + bhh[384+i];
    gb[i*4+2] = bih[768+i];
    gb[i*4+3] = bhh[768+i];
  }
}

// ---------------------------------------------------------------- main ----
__global__ __launch_bounds__(256, 1)
void gru_main(const float* __restrict__ ih, const float* __restrict__ plan,
              const float* __restrict__ gate, const float* __restrict__ istate,
              const u16* __restrict__ stream, const u16* __restrict__ wd2p,
              const u16* __restrict__ wxp, const float* __restrict__ gb,
              const float* __restrict__ bd1, const float* __restrict__ bd2,
              float* __restrict__ out)
{
  __shared__ __attribute__((aligned(16))) u16 wb[2][PHU];   // 49152 B
  __shared__ __attribute__((aligned(16))) u16 tsc[4][1280]; // 10240 B (32x40 per wave)
  __shared__ float sst[4][32][4];                           //  2048 B

  const int tid  = threadIdx.x;
  const int wave = tid >> 6, lane = tid & 63;
  const int m    = lane & 31, hl = lane >> 5;
  const int R0   = blockIdx.x*128 + wave*32;   // wave's 32 batch rows
  u16* ts = tsc[wave];

  const float gt    = gate[R0 + m];
  const float bd1v0 = bd1[m], bd1v1 = bd1[32+m];
  const float bd2v  = (m<3) ? bd2[m] : 0.f;
  u16x8 wd2f0 = *(const u16x8*)(wd2p + 0*512 + lane*8);
  u16x8 wd2f1 = *(const u16x8*)(wd2p + 1*512 + lane*8);
  u16x8 wd2f2 = *(const u16x8*)(wd2p + 2*512 + lane*8);
  u16x8 wd2f3 = *(const u16x8*)(wd2p + 3*512 + lane*8);

  if (lane < 32){
    const float* sp = istate + (size_t)(R0+lane)*3;
    sst[wave][lane][0]=sp[0]; sst[wave][lane][1]=sp[1];
    sst[wave][lane][2]=sp[2]; sst[wave][lane][3]=0.f;
  }

  // initial hidden -> A-frags: hold[kf] = h[m][kf*16 + hl*8 + j]
  u16x8 hold[24];
#pragma unroll
  for (int kf=0; kf<24; ++kf){
    const float* p = ih + (size_t)(R0+m)*384 + kf*16 + hl*8;
    float4 a = *(const float4*)p;
    float4 b = *(const float4*)(p+4);
    u16x8 v;
    v[0]=f2b(a.x); v[1]=f2b(a.y); v[2]=f2b(a.z); v[3]=f2b(a.w);
    v[4]=f2b(b.x); v[5]=f2b(b.y); v[6]=f2b(b.z); v[7]=f2b(b.w);
    hold[kf]=v;
  }

  const u16* srcb = stream + wave*3072 + lane*8;  // this wave's quarter + lane slot
  auto stage = [&](int ph, int bsel){
    const u16* s = srcb + (size_t)ph*PHU;
    u16* d = &wb[bsel][wave*3072];
#pragma unroll
    for (int ii=0; ii<6; ++ii) stage16(s + ii*512, d + ii*512);
  };

  stage(0, 0);
  vm_fence(); __syncthreads();
  int buf = 0, gp = 0;

#pragma unroll 1
  for (int t=0; t<TT; ++t){
    // ---- x = (state@Ws^T+bs) + gate*(plan@Wp^T+bp) via one padded-K MFMA per tile
    u16x8 a8;
    {
      float4 sv = *(const float4*)&sst[wave][m][0];
      const float* pp = plan + (size_t)(R0+m)*(TT*3) + t*3;
      float f0=sv.x, f1=sv.y, f2=sv.z, f3=1.f;
      float f4=gt*pp[0], f5=gt*pp[1], f6=gt*pp[2], f7=gt;
      if (hl){ a8[0]=0;a8[1]=0;a8[2]=0;a8[3]=0;a8[4]=0;a8[5]=0;a8[6]=0;a8[7]=0; }
      else { a8[0]=f2b(f0);a8[1]=f2b(f1);a8[2]=f2b(f2);a8[3]=f2b(f3);
             a8[4]=f2b(f4);a8[5]=f2b(f5);a8[6]=f2b(f6);a8[7]=f2b(f7); }
    }
    u16x8 xf[8];
#pragma unroll
    for (int tl=0; tl<4; ++tl){
      f32x16 ax;
#pragma unroll
      for (int r=0;r<16;++r) ax[r]=0.f;
      ax = mfma32(a8, *(const u16x8*)(wxp + tl*512 + lane*8), ax);
      // C-layout -> ts -> A-frags
#pragma unroll
      for (int r=0;r<16;++r){
        int row = (r&3) + ((r>>2)<<3) + 4*hl;
        ts[row*40 + m] = f2b(ax[r]);
      }
      lds_fence();
      xf[2*tl]   = *(const u16x8*)&ts[m*40 + hl*8];
      xf[2*tl+1] = *(const u16x8*)&ts[m*40 + 16 + hl*8];
      lds_fence();
    }

    u16x8 hnew[24];
#pragma unroll
    for (int c=0; c<12; ++c){
      f32x16 aR, aZ, aNI, aNH;
      {
        const float4 b4 = *(const float4*)(gb + (size_t)(c*32+m)*4);
#pragma unroll
        for (int r=0;r<16;++r){ aR[r]=b4.x; aZ[r]=b4.y; aNI[r]=b4.z; aNH[r]=b4.w; }
      }
      { // phase c*4: gi (r,z,n from x)
        int np = gp+1; stage(np, buf^1);
        const u16* W = wb[buf];
#pragma unroll
        for (int kf=0; kf<8; ++kf){
          u16x8 bR = *(const u16x8*)(W + (kf    )*512 + lane*8);
          u16x8 bZ = *(const u16x8*)(W + (8+kf  )*512 + lane*8);
          u16x8 bN = *(const u16x8*)(W + (16+kf )*512 + lane*8);
          aR  = mfma32(xf[kf], bR, aR);
          aZ  = mfma32(xf[kf], bZ, aZ);
          aNI = mfma32(xf[kf], bN, aNI);
        }
        vm_fence(); __syncthreads(); buf^=1; gp=np;
      }
      { // phase c*4+1: gh_r
        int np = gp+1; stage(np, buf^1);
        const u16* W = wb[buf];
#pragma unroll
        for (int kf=0; kf<24; ++kf)
          aR = mfma32(hold[kf], *(const u16x8*)(W + kf*512 + lane*8), aR);
        vm_fence(); __syncthreads(); buf^=1; gp=np;
      }
      { // phase c*4+2: gh_z
        int np = gp+1; stage(np, buf^1);
        const u16* W = wb[buf];
#pragma unroll
        for (int kf=0; kf<24; ++kf)
          aZ = mfma32(hold[kf], *(const u16x8*)(W + kf*512 + lane*8), aZ);
        vm_fence(); __syncthreads(); buf^=1; gp=np;
      }
      { // phase c*4+3: gh_n + GRU elementwise + h-frag rebuild
        int np = gp+1; stage(np, buf^1);
        const u16* W = wb[buf];
#pragma unroll
        for (int kf=0; kf<24; ++kf)
          aNH = mfma32(hold[kf], *(const u16x8*)(W + kf*512 + lane*8), aNH);
        // old h chunk -> ts (row-major [32][40])
        *(u16x8*)&ts[m*40 + hl*8]      = hold[2*c];
        *(u16x8*)&ts[m*40 + 16 + hl*8] = hold[2*c+1];
        lds_fence();
#pragma unroll
        for (int r=0;r<16;++r){
          int row = (r&3) + ((r>>2)<<3) + 4*hl;
          float rr = sigf(aR[r]);
          float zz = sigf(aZ[r]);
          float nn = tanh_(aNI[r] + rr*aNH[r]);
          int off = row*40 + m;
          float ho = b2f(ts[off]);             // old h (same lane wrote/reads pair)
          ts[off] = f2b((1.f-zz)*nn + zz*ho);  // new h
        }
        lds_fence();
        hnew[2*c]   = *(const u16x8*)&ts[m*40 + hl*8];
        hnew[2*c+1] = *(const u16x8*)&ts[m*40 + 16 + hl*8];
        vm_fence(); __syncthreads(); buf^=1; gp=np;
      }
    } // chunks

    // ---- decode: d1 = elu(h@Wd1^T + bd1) [2 tiles], then d2 via padded-N MFMA
    f32x16 a0, a1;
#pragma unroll
    for (int r=0;r<16;++r){ a0[r]=bd1v0; a1[r]=bd1v1; }
    { // phase 48: Wd1 tile 0
      int np = gp+1; stage(np, buf^1);
      const u16* W = wb[buf];
#pragma unroll
      for (int kf=0; kf<24; ++kf)
        a0 = mfma32(hnew[kf], *(const u16x8*)(W + kf*512 + lane*8), a0);
      vm_fence(); __syncthreads(); buf^=1; gp=np;
    }
    { // phase 49: Wd1 tile 1 (+ epilogue); next stage wraps to phase 0
      int np = (gp+1 == NPH) ? 0 : gp+1;
      stage(np, buf^1);
      const u16* W = wb[buf];
#pragma unroll
      for (int kf=0; kf<24; ++kf)
        a1 = mfma32(hnew[kf], *(const u16x8*)(W + kf*512 + lane*8), a1);

      f32x16 ao;
#pragma unroll
      for (int r=0;r<16;++r) ao[r]=0.f;
      // pass 0: d1 units 0..31
#pragma unroll
      for (int r=0;r<16;++r){
        int row = (r&3) + ((r>>2)<<3) + 4*hl;
        float e = a0[r]; e = e>0.f ? e : (__expf(e)-1.f);
        ts[row*40 + m] = f2b(e);
      }
      lds_fence();
      {
        u16x8 af0 = *(const u16x8*)&ts[m*40 + hl*8];
        u16x8 af1 = *(const u16x8*)&ts[m*40 + 16 + hl*8];
        ao = mfma32(af0, wd2f0, ao);
        ao = mfma32(af1, wd2f1, ao);
      }
      lds_fence();
      // pass 1: d1 units 32..63
#pragma unroll
      for (int r=0;r<16;++r){
        int row = (r&3) + ((r>>2)<<3) + 4*hl;
        float e = a1[r]; e = e>0.f ? e : (__expf(e)-1.f);
        ts[row*40 + m] = f2b(e);
      }
      lds_fence();
      {
        u16x8 af0 = *(const u16x8*)&ts[m*40 + hl*8];
        u16x8 af1 = *(const u16x8*)&ts[m*40 + 16 + hl*8];
        ao = mfma32(af0, wd2f2, ao);
        ao = mfma32(af1, wd2f3, ao);
      }
      // out + state update (C cols 0..2 valid)
#pragma unroll
      for (int r=0;r<16;++r){
        int row = (r&3) + ((r>>2)<<3) + 4*hl;
        if (m < 3){
          float ns = sst[wave][row][m] + ao[r] + bd2v;
          out[(size_t)(R0+row)*(TT*3) + t*3 + m] = ns;
          sst[wave][row][m] = ns;
        }
      }
      vm_fence(); __syncthreads(); buf^=1; gp=np;
    }
#pragma unroll
    for (int kf=0; kf<24; ++kf) hold[kf] = hnew[kf];
  } // t
}

// -------------------------------------------------------------- launch ----
extern "C" void kernel_launch(void* const* d_in, const int* in_sizes, int n_in,
                              void* d_out, int out_size, void* d_ws, size_t ws_size,
                              hipStream_t stream)
{
  (void)in_sizes; (void)n_in; (void)out_size; (void)ws_size;
  const float* ih     = (const float*)d_in[0];
  const float* plan   = (const float*)d_in[1];
  const float* gatep  = (const float*)d_in[2];
  const float* istate = (const float*)d_in[3];
  const float* Wp     = (const float*)d_in[4];
  const float* bp     = (const float*)d_in[5];
  const float* Ws     = (const float*)d_in[6];
  const float* bs     = (const float*)d_in[7];
  const float* Wih    = (const float*)d_in[8];
  const float* bih    = (const float*)d_in[9];
  const float* Whh    = (const float*)d_in[10];
  const float* bhh    = (const float*)d_in[11];
  const float* Wd1    = (const float*)d_in[12];
  const float* bd1    = (const float*)d_in[13];
  const float* Wd2    = (const float*)d_in[14];
  const float* bd2    = (const float*)d_in[15];

  // workspace layout (~1.25 MB)
  u16*   wstream = (u16*)d_ws;                         // 614400 u16 = 1228800 B
  u16*   wd2p    = (u16*)((char*)d_ws + 1228800);      //   2048 u16 =    4096 B
  u16*   wxp     = (u16*)((char*)d_ws + 1232896);      //   2048 u16 =    4096 B
  float* gb      = (float*)((char*)d_ws + 1236992);    //   1536 f32 =    6144 B

  prep_kernel<<<1728, 256, 0, stream>>>(Wih, Whh, Wd1, Wd2, bih, bhh, Ws, bs, Wp, bp,
                                        wstream, wd2p, wxp, gb);
  gru_main<<<256, 256, 0, stream>>>(ih, plan, gatep, istate,
                                    wstream, wd2p, wxp, gb, bd1, bd2, (float*)d_out);
}